// Round 2
// baseline (1013.876 us; speedup 1.0000x reference)
//
#include <hip/hip_runtime.h>
#include <hip/hip_bf16.h>

// Problem constants (fixed shapes from reference)
constexpr int Bb  = 8;
constexpr int Ss  = 2048;
constexpr int Ee  = 128;
constexpr int Hh  = 8;
constexpr int HSs = 16;
constexpr int QKVSZ = Bb * Hh * Ss * HSs;  // 2,097,152 elements per tensor

// ---------------------------------------------------------------------------
// Kernel A: fused Q/K/V projection (all fp32).
// One block per (b,s) row. x row (128 floats) staged in LDS.
// 384 threads: thread t computes one of the 3*128 output dots.
// Output layout: [B,H,S,hs] fp32 so attention reads k/v rows contiguously.
// ---------------------------------------------------------------------------
__global__ __launch_bounds__(384) void qkv_kernel(
    const float* __restrict__ x,
    const float* __restrict__ Wk,
    const float* __restrict__ Wq,
    const float* __restrict__ Wv,
    float* __restrict__ qo, float* __restrict__ ko, float* __restrict__ vo)
{
    int row = blockIdx.x;            // b*S + s
    __shared__ float xs[Ee];
    int tid = threadIdx.x;
    if (tid < Ee) xs[tid] = x[row * Ee + tid];
    __syncthreads();

    int c     = tid & 127;           // output channel (= h*16+d) within [128,128] weights
    int which = tid >> 7;            // 0=q, 1=k, 2=v
    const float* W = (which == 0) ? Wq : ((which == 1) ? Wk : Wv);
    const float4* wr = (const float4*)(W + c * Ee);

    float acc = 0.f;
#pragma unroll
    for (int i = 0; i < Ee / 4; ++i) {
        float4 w = wr[i];
        acc += xs[4 * i + 0] * w.x;
        acc += xs[4 * i + 1] * w.y;
        acc += xs[4 * i + 2] * w.z;
        acc += xs[4 * i + 3] * w.w;
    }

    int b = row >> 11;               // row / 2048
    int s = row & 2047;
    int h = c >> 4;
    int d = c & 15;
    float* dst = (which == 0) ? qo : ((which == 1) ? ko : vo);
    dst[((b * Hh + h) * Ss + s) * HSs + d] = acc;
}

// ---------------------------------------------------------------------------
// Kernel B: flash-style attention with online softmax.
// One thread per query; 256 queries per block; block owns one (b,h, q-tile).
// K/V tiles of KT keys staged in LDS (all lanes read the same key -> broadcast,
// bank-conflict free). Scores scaled by *4 (reference MULTIPLIES by sqrt(hs)).
// ---------------------------------------------------------------------------
constexpr int KT = 32;
__global__ __launch_bounds__(256) void attn_kernel(
    const float* __restrict__ qg, const float* __restrict__ kg,
    const float* __restrict__ vg, float* __restrict__ og)
{
    const int QB = 256;
    const int tiles_per_seq = Ss / QB;      // 8
    int bh = blockIdx.x / tiles_per_seq;    // b*H + h
    int qt = blockIdx.x % tiles_per_seq;
    int s  = qt * QB + threadIdx.x;

    const float4* qp = (const float4*)(qg + (bh * Ss + s) * HSs);
    float qr[HSs];
#pragma unroll
    for (int i = 0; i < HSs / 4; ++i) {
        float4 t = qp[i];
        qr[4 * i + 0] = t.x * 4.f;   // fold the *sqrt(16) scale into q
        qr[4 * i + 1] = t.y * 4.f;
        qr[4 * i + 2] = t.z * 4.f;
        qr[4 * i + 3] = t.w * 4.f;
    }

    __shared__ float ks[KT * HSs];
    __shared__ float vs[KT * HSs];

    float acc[HSs];
#pragma unroll
    for (int d = 0; d < HSs; ++d) acc[d] = 0.f;
    float m = -1e30f, l = 0.f;

    for (int t0 = 0; t0 < Ss; t0 += KT) {
        __syncthreads();
        const float4* kb = (const float4*)(kg + (bh * Ss + t0) * HSs);
        const float4* vb = (const float4*)(vg + (bh * Ss + t0) * HSs);
        if (threadIdx.x < KT * HSs / 4) {   // 128 float4s per matrix
            ((float4*)ks)[threadIdx.x] = kb[threadIdx.x];
            ((float4*)vs)[threadIdx.x] = vb[threadIdx.x];
        }
        __syncthreads();

        float sc[KT];
        float tmax = -1e30f;
#pragma unroll
        for (int t = 0; t < KT; ++t) {
            float sum = 0.f;
#pragma unroll
            for (int d = 0; d < HSs; ++d) sum += qr[d] * ks[t * HSs + d];
            sc[t] = sum;
            tmax = fmaxf(tmax, sum);
        }
        float mnew = fmaxf(m, tmax);
        float corr = __expf(m - mnew);
        l *= corr;
#pragma unroll
        for (int d = 0; d < HSs; ++d) acc[d] *= corr;
#pragma unroll
        for (int t = 0; t < KT; ++t) {
            float p = __expf(sc[t] - mnew);
            l += p;
#pragma unroll
            for (int d = 0; d < HSs; ++d) acc[d] += p * vs[t * HSs + d];
        }
        m = mnew;
    }

    float inv = 1.f / l;
    int b = bh / Hh, h = bh % Hh;
    float* op = og + (b * Ss + s) * Ee + h * HSs;   // [B,S,H*hs] concat layout
#pragma unroll
    for (int d = 0; d < HSs; ++d) op[d] = acc[d] * inv;
}

// ---------------------------------------------------------------------------
// Kernel C: output projection  out[row,e] = sum_c attn[row,c]*Wp[e,c] + bp[e]
// One block per row (128 threads = one output each), attn row in LDS.
// ---------------------------------------------------------------------------
__global__ __launch_bounds__(128) void proj_kernel(
    const float* __restrict__ attn,
    const float* __restrict__ Wp,
    const float* __restrict__ bp,
    float* __restrict__ out)
{
    int row = blockIdx.x;
    __shared__ float as[Ee];
    int e = threadIdx.x;
    as[e] = attn[row * Ee + e];
    __syncthreads();

    const float4* wr = (const float4*)(Wp + e * Ee);
    float acc = bp[e];
#pragma unroll
    for (int i = 0; i < Ee / 4; ++i) {
        float4 w = wr[i];
        acc += as[4 * i + 0] * w.x;
        acc += as[4 * i + 1] * w.y;
        acc += as[4 * i + 2] * w.z;
        acc += as[4 * i + 3] * w.w;
    }
    out[row * Ee + e] = acc;
}

// ---------------------------------------------------------------------------
extern "C" void kernel_launch(void* const* d_in, const int* in_sizes, int n_in,
                              void* d_out, int out_size, void* d_ws, size_t ws_size,
                              hipStream_t stream)
{
    const float* x  = (const float*)d_in[0];
    const float* Wk = (const float*)d_in[1];
    const float* Wq = (const float*)d_in[2];
    const float* Wv = (const float*)d_in[3];
    const float* Wp = (const float*)d_in[4];
    const float* bp = (const float*)d_in[5];
    float* out = (float*)d_out;

    float* ws  = (float*)d_ws;
    float* q    = ws;
    float* k    = ws + (size_t)QKVSZ;
    float* v    = ws + (size_t)2 * QKVSZ;
    float* attn = ws + (size_t)3 * QKVSZ;   // total 32 MiB fp32 scratch

    qkv_kernel<<<Bb * Ss, 384, 0, stream>>>(x, Wk, Wq, Wv, q, k, v);
    attn_kernel<<<Bb * Hh * (Ss / 256), 256, 0, stream>>>(q, k, v, attn);
    proj_kernel<<<Bb * Ss, 128, 0, stream>>>(attn, Wp, bp, out);
}

// Round 5
// 293.129 us; speedup vs baseline: 3.4588x; 3.4588x over previous
//
#include <hip/hip_runtime.h>
#include <hip/hip_bf16.h>

// Problem constants
constexpr int Bb  = 8;
constexpr int Ss  = 2048;
constexpr int Ee  = 128;
constexpr int Hh  = 8;
constexpr int HSs = 16;
constexpr int QKVSZ = Bb * Hh * Ss * HSs;  // 2,097,152 elements per tensor

typedef _Float16 f16;
typedef __attribute__((ext_vector_type(8))) _Float16 f16x8;   // 8 f16 = 4 VGPRs
typedef __attribute__((ext_vector_type(4))) float f32x4;

// RTZ packed fp32x2 -> fp16x2 (one v_cvt_pkrtz_f16_f32); low half = first arg
__device__ __forceinline__ unsigned pack_rtz(float lo, float hi) {
    union { __fp16 __attribute__((ext_vector_type(2))) h; unsigned u; } c;
    c.h = __builtin_amdgcn_cvt_pkrtz(lo, hi);
    return c.u;
}
// RNE pair pack (two v_cvt_f16_f32, RNE rounding)
__device__ __forceinline__ unsigned pack_rne(float lo, float hi) {
    union { __attribute__((ext_vector_type(2))) _Float16 h; unsigned u; } c;
    c.h[0] = (f16)lo; c.h[1] = (f16)hi;
    return c.u;
}

// ---------------------------------------------------------------------------
// Kernel A: fused Q/K/V projection, 32 rows per block (weight reuse x32).
// 384 threads: thread owns one (which,c) output channel across 32 rows.
// LDS x-tile reads are wave-uniform -> LDS broadcast, conflict-free.
// ---------------------------------------------------------------------------
__global__ __launch_bounds__(384) void qkv_kernel(
    const float* __restrict__ x, const float* __restrict__ Wk,
    const float* __restrict__ Wq, const float* __restrict__ Wv,
    float* __restrict__ qo, float* __restrict__ ko, float* __restrict__ vo)
{
    constexpr int RT = 32;
    __shared__ __align__(16) float xs[RT * Ee];   // 16 KB
    const int r0 = blockIdx.x * RT;
    {
        const float4* xp = (const float4*)(x + (size_t)r0 * Ee);
        float4* s4 = (float4*)xs;
        for (int idx = threadIdx.x; idx < RT * Ee / 4; idx += 384) s4[idx] = xp[idx];
    }
    __syncthreads();

    const int c = threadIdx.x & 127;
    const int which = threadIdx.x >> 7;          // 0=q,1=k,2=v
    const float* W = (which == 0) ? Wq : ((which == 1) ? Wk : Wv);
    const float4* wr = (const float4*)(W + (size_t)c * Ee);

    float acc[RT];
#pragma unroll
    for (int r = 0; r < RT; ++r) acc[r] = 0.f;

    for (int i = 0; i < Ee / 4; ++i) {
        float4 w = wr[i];
#pragma unroll
        for (int r = 0; r < RT; ++r) {
            const float4 xv = *(const float4*)&xs[r * Ee + 4 * i];
            acc[r] += xv.x * w.x + xv.y * w.y + xv.z * w.z + xv.w * w.w;
        }
    }

    const int b = r0 >> 11, s0 = r0 & 2047, h = c >> 4, d = c & 15;
    float* dst = (which == 0) ? qo : ((which == 1) ? ko : vo);
    float* base = dst + ((size_t)(b * Hh + h) * Ss + s0) * HSs + d;
#pragma unroll
    for (int r = 0; r < RT; ++r) base[r * HSs] = acc[r];
}

// ---------------------------------------------------------------------------
// Kernel B: MFMA flash attention (fp16 fragments, fp32 softmax/accum).
// Block = 4 waves, same (b,h); wave owns a 16-query tile; 32-key chunks.
// Scores computed transposed: S^T[key][q] = K(A) x Q^T(B), mfma 16x16x32 f16
// (K-dim = hs = 16, zero-padded to 32). Softmax state (m,l) per q = lane&15.
// PV computed as O^T[d][q] = Vt(A) x P^T(B); out written as float4.
// Layouts (dtype-independent, guide §3/m89/m121): A[m=lane&15][k=quad*8+j],
// B[k=quad*8+j][n=lane&15], C/D[row=quad*4+reg][col=lane&15].
// ---------------------------------------------------------------------------
constexpr float QSCALE = 5.770780163555854f;  // 4 * log2(e): *sqrt(hs) scale + exp2 base

__global__ __launch_bounds__(256) void attn_kernel(
    const float* __restrict__ qg, const float* __restrict__ kg,
    const float* __restrict__ vg, float* __restrict__ og)
{
    __shared__ __align__(16) f16 Ks[32 * 32];     // [key][dslot0..31], 2 KB
    __shared__ __align__(16) f16 Vt[16 * 32];     // [d][key], 1 KB
    __shared__ __align__(16) f16 Pt[4][16 * 32];  // per-wave [q][key], 4 KB

    const int bh   = blockIdx.x >> 5;          // 0..63
    const int qgrp = blockIdx.x & 31;
    const int wv   = threadIdx.x >> 6;
    const int lane = threadIdx.x & 63;
    const int quad = lane >> 4;
    const int l15  = lane & 15;
    const int qbase = (qgrp * 4 + wv) * 16;

    // zero the d>=16 half of Ks rows once (K-dim padding); no overlap with staging
    {
        int t = threadIdx.x;  // key = t>>3, dword slot = t&7 within d 16..31
        *(unsigned*)&Ks[(t >> 3) * 32 + 16 + 2 * (t & 7)] = 0u;
    }

    // Q B-frag (fixed for whole K loop): lane holds Q[q=l15][d=quad*8+j], 0 for d>=16
    f16x8 qf = {0, 0, 0, 0, 0, 0, 0, 0};
    if (quad < 2) {
        const float* qp = qg + ((size_t)bh * Ss + qbase + l15) * HSs + quad * 8;
#pragma unroll
        for (int j = 0; j < 8; ++j) qf[j] = (f16)(qp[j] * QSCALE);
    }

    const f32x4 z4 = {0.f, 0.f, 0.f, 0.f};
    f32x4 o = z4;
    float m = -1e30f, l = 0.f;

    for (int t0 = 0; t0 < Ss; t0 += 32) {
        __syncthreads();   // previous iteration's readers done before overwrite
        {   // stage 32 keys x 16 d of K and V (fp16 RNE); 2 elems per thread each
            const int t = threadIdx.x;
            const float2* kp = (const float2*)(kg + ((size_t)bh * Ss + t0) * HSs);
            const float2* vp = (const float2*)(vg + ((size_t)bh * Ss + t0) * HSs);
            float2 kvv = kp[t];
            float2 vvv = vp[t];
            const int e = 2 * t, key = e >> 4, d = e & 15;   // d even
            *(unsigned*)&Ks[key * 32 + d] = pack_rne(kvv.x, kvv.y);
            Vt[d * 32 + key]       = (f16)vvv.x;
            Vt[(d + 1) * 32 + key] = (f16)vvv.y;
        }
        __syncthreads();

        // S^T = K x Q^T : A-frag = K row (key = l15 / l15+16), padded K-dim
        f16x8 ka0 = *(const f16x8*)&Ks[l15 * 32 + quad * 8];
        f16x8 ka1 = *(const f16x8*)&Ks[(16 + l15) * 32 + quad * 8];
        f32x4 s0 = __builtin_amdgcn_mfma_f32_16x16x32_f16(ka0, qf, z4, 0, 0, 0);
        f32x4 s1 = __builtin_amdgcn_mfma_f32_16x16x32_f16(ka1, qf, z4, 0, 0, 0);
        // lane holds S^T[key = quad*4+reg (+16)][q = l15]

        // online softmax over 32 keys (reduction = in-lane + xor16 + xor32)
        float mx = fmaxf(fmaxf(fmaxf(s0.x, s0.y), fmaxf(s0.z, s0.w)),
                         fmaxf(fmaxf(s1.x, s1.y), fmaxf(s1.z, s1.w)));
        mx = fmaxf(mx, __shfl_xor(mx, 16, 64));
        mx = fmaxf(mx, __shfl_xor(mx, 32, 64));
        const float mnew = fmaxf(m, mx);
        const float corr = __builtin_amdgcn_exp2f(m - mnew);
        s0.x = __builtin_amdgcn_exp2f(s0.x - mnew);
        s0.y = __builtin_amdgcn_exp2f(s0.y - mnew);
        s0.z = __builtin_amdgcn_exp2f(s0.z - mnew);
        s0.w = __builtin_amdgcn_exp2f(s0.w - mnew);
        s1.x = __builtin_amdgcn_exp2f(s1.x - mnew);
        s1.y = __builtin_amdgcn_exp2f(s1.y - mnew);
        s1.z = __builtin_amdgcn_exp2f(s1.z - mnew);
        s1.w = __builtin_amdgcn_exp2f(s1.w - mnew);
        float rs = (s0.x + s0.y) + (s0.z + s0.w) + (s1.x + s1.y) + (s1.z + s1.w);
        rs += __shfl_xor(rs, 16, 64);
        rs += __shfl_xor(rs, 32, 64);
        l = l * corr + rs;
        o.x *= corr; o.y *= corr; o.z *= corr; o.w *= corr;
        m = mnew;

        // P^T -> per-wave LDS: row q=l15, cols key=quad*4+reg (+16); b64 writes
        unsigned pw0 = pack_rtz(s0.x, s0.y), pw1 = pack_rtz(s0.z, s0.w);
        unsigned pw2 = pack_rtz(s1.x, s1.y), pw3 = pack_rtz(s1.z, s1.w);
        {
            unsigned* p0 = (unsigned*)&Pt[wv][l15 * 32 + quad * 4];
            p0[0] = pw0; p0[1] = pw1;
            unsigned* p1 = (unsigned*)&Pt[wv][l15 * 32 + 16 + quad * 4];
            p1[0] = pw2; p1[1] = pw3;
        }
        // wave-internal cross-lane LDS dependence: drain LDS before frag reads
        asm volatile("s_waitcnt lgkmcnt(0)" ::: "memory");

        // O^T += Vt(A) x P^T(B)
        f16x8 va = *(const f16x8*)&Vt[l15 * 32 + quad * 8];        // m = d = l15
        f16x8 pb = *(const f16x8*)&Pt[wv][l15 * 32 + quad * 8];    // n = q = l15
        o = __builtin_amdgcn_mfma_f32_16x16x32_f16(va, pb, o, 0, 0, 0);
    }

    // normalize and write: lane has q=l15, d = quad*4 + reg -> float4
    const float inv = 1.f / l;
    const int b = bh >> 3, h = bh & 7;
    float4 r4;
    r4.x = o.x * inv; r4.y = o.y * inv; r4.z = o.z * inv; r4.w = o.w * inv;
    float* op = og + ((size_t)b * Ss + qbase + l15) * Ee + h * HSs + quad * 4;
    *(float4*)op = r4;
}

// ---------------------------------------------------------------------------
// Kernel C: output projection, 16 rows per block (weight reuse x16).
// 128 threads: thread owns output channel e across 16 rows; coalesced store.
// ---------------------------------------------------------------------------
__global__ __launch_bounds__(128) void proj_kernel(
    const float* __restrict__ attn, const float* __restrict__ Wp,
    const float* __restrict__ bp, float* __restrict__ out)
{
    constexpr int RT = 16;
    __shared__ __align__(16) float as_[RT * Ee];  // 8 KB
    const int r0 = blockIdx.x * RT;
    {
        const float4* ap = (const float4*)(attn + (size_t)r0 * Ee);
        float4* s4 = (float4*)as_;
        for (int idx = threadIdx.x; idx < RT * Ee / 4; idx += 128) s4[idx] = ap[idx];
    }
    __syncthreads();

    const int e = threadIdx.x;
    const float4* wr = (const float4*)(Wp + (size_t)e * Ee);
    const float bias = bp[e];
    float acc[RT];
#pragma unroll
    for (int r = 0; r < RT; ++r) acc[r] = bias;

    for (int i = 0; i < Ee / 4; ++i) {
        float4 w = wr[i];
#pragma unroll
        for (int r = 0; r < RT; ++r) {
            const float4 xv = *(const float4*)&as_[r * Ee + 4 * i];
            acc[r] += xv.x * w.x + xv.y * w.y + xv.z * w.z + xv.w * w.w;
        }
    }
#pragma unroll
    for (int r = 0; r < RT; ++r) out[(size_t)(r0 + r) * Ee + e] = acc[r];
}

// ---------------------------------------------------------------------------
extern "C" void kernel_launch(void* const* d_in, const int* in_sizes, int n_in,
                              void* d_out, int out_size, void* d_ws, size_t ws_size,
                              hipStream_t stream)
{
    const float* x  = (const float*)d_in[0];
    const float* Wk = (const float*)d_in[1];
    const float* Wq = (const float*)d_in[2];
    const float* Wv = (const float*)d_in[3];
    const float* Wp = (const float*)d_in[4];
    const float* bp = (const float*)d_in[5];
    float* out = (float*)d_out;

    float* ws   = (float*)d_ws;
    float* q    = ws;
    float* k    = ws + (size_t)QKVSZ;
    float* v    = ws + (size_t)2 * QKVSZ;
    float* attn = ws + (size_t)3 * QKVSZ;   // 32 MiB total fp32 scratch

    qkv_kernel<<<Bb * Ss / 32, 384, 0, stream>>>(x, Wk, Wq, Wv, q, k, v);
    attn_kernel<<<Bb * Hh * (Ss / 64), 256, 0, stream>>>(q, k, v, attn);
    proj_kernel<<<Bb * Ss / 16, 128, 0, stream>>>(attn, Wp, bp, out);
}

// Round 6
// 217.664 us; speedup vs baseline: 4.6580x; 1.3467x over previous
//
#include <hip/hip_runtime.h>
#include <hip/hip_bf16.h>

// Problem constants
constexpr int Bb  = 8;
constexpr int Ss  = 2048;
constexpr int Ee  = 128;
constexpr int Hh  = 8;
constexpr int HSs = 16;
constexpr int QKVSZ = Bb * Hh * Ss * HSs;  // 2,097,152 elements per tensor

typedef _Float16 f16;
typedef __attribute__((ext_vector_type(8)))  _Float16 f16x8;   // 8 f16 = 4 VGPRs
typedef __attribute__((ext_vector_type(4)))  float f32x4;
typedef __attribute__((ext_vector_type(16))) float f32x16;

// RTZ packed fp32x2 -> fp16x2 (one v_cvt_pkrtz_f16_f32); low half = first arg
__device__ __forceinline__ unsigned pack_rtz(float lo, float hi) {
    union { __fp16 __attribute__((ext_vector_type(2))) h; unsigned u; } c;
    c.h = __builtin_amdgcn_cvt_pkrtz(lo, hi);
    return c.u;
}
// RNE pair pack (two v_cvt_f16_f32, RNE rounding)
__device__ __forceinline__ unsigned pack_rne(float lo, float hi) {
    union { __attribute__((ext_vector_type(2))) _Float16 h; unsigned u; } c;
    c.h[0] = (f16)lo; c.h[1] = (f16)hi;
    return c.u;
}

// ---------------------------------------------------------------------------
// Kernel A: fused Q/K/V projection, 32 rows per block (weight reuse x32).
// ---------------------------------------------------------------------------
__global__ __launch_bounds__(384) void qkv_kernel(
    const float* __restrict__ x, const float* __restrict__ Wk,
    const float* __restrict__ Wq, const float* __restrict__ Wv,
    float* __restrict__ qo, float* __restrict__ ko, float* __restrict__ vo)
{
    constexpr int RT = 32;
    __shared__ __align__(16) float xs[RT * Ee];   // 16 KB
    const int r0 = blockIdx.x * RT;
    {
        const float4* xp = (const float4*)(x + (size_t)r0 * Ee);
        float4* s4 = (float4*)xs;
        for (int idx = threadIdx.x; idx < RT * Ee / 4; idx += 384) s4[idx] = xp[idx];
    }
    __syncthreads();

    const int c = threadIdx.x & 127;
    const int which = threadIdx.x >> 7;          // 0=q,1=k,2=v
    const float* W = (which == 0) ? Wq : ((which == 1) ? Wk : Wv);
    const float4* wr = (const float4*)(W + (size_t)c * Ee);

    float acc[RT];
#pragma unroll
    for (int r = 0; r < RT; ++r) acc[r] = 0.f;

    for (int i = 0; i < Ee / 4; ++i) {
        float4 w = wr[i];
#pragma unroll
        for (int r = 0; r < RT; ++r) {
            const float4 xv = *(const float4*)&xs[r * Ee + 4 * i];
            acc[r] += xv.x * w.x + xv.y * w.y + xv.z * w.z + xv.w * w.w;
        }
    }

    const int b = r0 >> 11, s0 = r0 & 2047, h = c >> 4, d = c & 15;
    float* dst = (which == 0) ? qo : ((which == 1) ? ko : vo);
    float* base = dst + ((size_t)(b * Hh + h) * Ss + s0) * HSs + d;
#pragma unroll
    for (int r = 0; r < RT; ++r) base[r * HSs] = acc[r];
}

// ---------------------------------------------------------------------------
// Kernel B: MFMA flash attention, 32x32x16 shapes.
// Block = 4 waves, same (b,h); wave owns a 32-query tile; 32-key chunks.
//  S^T[key][q] = K(A, 32x16 exact) x Q^T(B)        -- 1 mfma_32x32x16_f16
//  O^T[d][q]  += V^T(A, d rows 16..31 zero) x P^T  -- 2 mfma_32x32x16_f16
// 32x32x16 layouts (m74/m101, dtype-indep): A[m=lane&31][k=8*(lane>>5)+j],
// B[k=8*(lane>>5)+j][n=lane&31], C/D[row=(reg&3)+8*(reg>>2)+4*(lane>>5)][col=lane&31].
// q = lane&31 in BOTH C layouts -> softmax state is lane-local (one xor32 per reduce).
// P^T C->B relayout done in-register with 4 shfl_xor(32) + selects (no LDS trip).
// LDS strides: Ks 48B rows, Vt 80B rows (odd multiples of 16B -> even bank spread).
// ---------------------------------------------------------------------------
constexpr float QSCALE = 5.770780163555854f;  // 4 * log2(e): *sqrt(hs) scale, exp2 base

__global__ __launch_bounds__(256) void attn_kernel(
    const float* __restrict__ qg, const float* __restrict__ kg,
    const float* __restrict__ vg, float* __restrict__ og)
{
    __shared__ __align__(16) f16 Ks[32 * 24];   // [key][d 0..15], row 48B, 1.5KB
    __shared__ __align__(16) f16 Vt[32 * 40];   // [d][key], rows 16..31 zero, 2.5KB

    const int bh   = blockIdx.x >> 4;           // 0..63
    const int qblk = blockIdx.x & 15;
    const int wv   = threadIdx.x >> 6;
    const int lane = threadIdx.x & 63;
    const int h    = lane >> 5;                 // half-wave index
    const int q31  = lane & 31;
    const int qbase = qblk * 128 + wv * 32;

    // zero Vt rows 16..31 once (PV M-padding); staged writes never touch them
    for (int i = threadIdx.x; i < 320; i += 256) ((unsigned*)Vt)[320 + i] = 0u;

    // Q B-frag (whole K loop): lane holds Q[q=q31][d=8h+j] * QSCALE
    f16x8 qf;
    {
        const float* qp = qg + ((size_t)bh * Ss + qbase + q31) * HSs + 8 * h;
#pragma unroll
        for (int j = 0; j < 8; ++j) qf[j] = (f16)(qp[j] * QSCALE);
    }

    // prefetch chunk 0 (float2/thread of K and V)
    const float2* kp = (const float2*)(kg + (size_t)bh * Ss * HSs) + threadIdx.x;
    const float2* vp = (const float2*)(vg + (size_t)bh * Ss * HSs) + threadIdx.x;
    float2 kreg = *kp, vreg = *vp;

    f32x16 acc = {};
    float m = -1e30f, l = 0.f;
    const int skey = threadIdx.x >> 3;          // staging: key, d pair
    const int sd   = (2 * threadIdx.x) & 15;

    for (int it = 0; it < Ss / 32; ++it) {
        __syncthreads();   // previous chunk's readers done
        *(unsigned*)&Ks[skey * 24 + sd] = pack_rne(kreg.x, kreg.y);
        Vt[sd * 40 + skey]       = (f16)vreg.x;
        Vt[(sd + 1) * 40 + skey] = (f16)vreg.y;
        __syncthreads();
        if (it < Ss / 32 - 1) { kp += 256; vp += 256; kreg = *kp; vreg = *vp; }

        // S^T = K x Q^T (keys = M = 32, d = K = 16 exact)
        f16x8 ka = *(const f16x8*)&Ks[q31 * 24 + 8 * h];
        f32x16 st = __builtin_amdgcn_mfma_f32_32x32x16_f16(ka, qf, (f32x16){}, 0, 0, 0);
        // lane holds S^T[key=(r&3)+8*(r>>2)+4h][q=q31], r=0..15

        // online softmax (16 in-lane + one xor32 per reduction)
        float mx = st[0];
#pragma unroll
        for (int i = 1; i < 16; ++i) mx = fmaxf(mx, st[i]);
        mx = fmaxf(mx, __shfl_xor(mx, 32, 64));
        const float mnew = fmaxf(m, mx);
        const float corr = __builtin_amdgcn_exp2f(m - mnew);
        float p[16];
        float rs = 0.f;
#pragma unroll
        for (int i = 0; i < 16; ++i) { p[i] = __builtin_amdgcn_exp2f(st[i] - mnew); rs += p[i]; }
        rs += __shfl_xor(rs, 32, 64);
        l = l * corr + rs;
#pragma unroll
        for (int r = 0; r < 8; ++r) acc[r] *= corr;   // only d<16 regs live
        m = mnew;

        // pack P^T pairs: pw[r] covers keys {base, base+1}, see mapping above
        unsigned pw[8];
#pragma unroll
        for (int r = 0; r < 8; ++r) pw[r] = pack_rtz(p[2 * r], p[2 * r + 1]);

        // C->B relayout via half-wave exchange (partner = lane^32)
        unsigned exa = (unsigned)__shfl_xor((int)(h ? pw[0] : pw[2]), 32, 64);
        unsigned exb = (unsigned)__shfl_xor((int)(h ? pw[1] : pw[3]), 32, 64);
        unsigned exc = (unsigned)__shfl_xor((int)(h ? pw[4] : pw[6]), 32, 64);
        unsigned exd = (unsigned)__shfl_xor((int)(h ? pw[5] : pw[7]), 32, 64);
        union { unsigned u[4]; f16x8 v; } B1, B2;
        if (h == 0) {
            B1.u[0] = pw[0]; B1.u[1] = pw[1]; B1.u[2] = exa; B1.u[3] = exb;
            B2.u[0] = pw[4]; B2.u[1] = pw[5]; B2.u[2] = exc; B2.u[3] = exd;
        } else {
            B1.u[0] = exa; B1.u[1] = exb; B1.u[2] = pw[2]; B1.u[3] = pw[3];
            B2.u[0] = exc; B2.u[1] = exd; B2.u[2] = pw[6]; B2.u[3] = pw[7];
        }

        // O^T += V^T x P^T  (keys 0..15, then 16..31)
        f16x8 va1 = *(const f16x8*)&Vt[q31 * 40 + 8 * h];
        f16x8 va2 = *(const f16x8*)&Vt[q31 * 40 + 16 + 8 * h];
        acc = __builtin_amdgcn_mfma_f32_32x32x16_f16(va1, B1.v, acc, 0, 0, 0);
        acc = __builtin_amdgcn_mfma_f32_32x32x16_f16(va2, B2.v, acc, 0, 0, 0);
    }

    // write: lane owns q=q31, d in {4h..4h+3} (regs 0-3) and {8+4h..} (regs 4-7)
    const float inv = 1.f / l;
    const int b = bh >> 3, head = bh & 7;
    float* op = og + ((size_t)b * Ss + qbase + q31) * Ee + head * HSs + 4 * h;
    float4 r0 = { acc[0] * inv, acc[1] * inv, acc[2] * inv, acc[3] * inv };
    float4 r1 = { acc[4] * inv, acc[5] * inv, acc[6] * inv, acc[7] * inv };
    *(float4*)op = r0;
    *(float4*)(op + 8) = r1;
}

// ---------------------------------------------------------------------------
// Kernel C: output projection, 16 rows per block (weight reuse x16).
// ---------------------------------------------------------------------------
__global__ __launch_bounds__(128) void proj_kernel(
    const float* __restrict__ attn, const float* __restrict__ Wp,
    const float* __restrict__ bp, float* __restrict__ out)
{
    constexpr int RT = 16;
    __shared__ __align__(16) float as_[RT * Ee];  // 8 KB
    const int r0 = blockIdx.x * RT;
    {
        const float4* ap = (const float4*)(attn + (size_t)r0 * Ee);
        float4* s4 = (float4*)as_;
        for (int idx = threadIdx.x; idx < RT * Ee / 4; idx += 128) s4[idx] = ap[idx];
    }
    __syncthreads();

    const int e = threadIdx.x;
    const float4* wr = (const float4*)(Wp + (size_t)e * Ee);
    const float bias = bp[e];
    float acc[RT];
#pragma unroll
    for (int r = 0; r < RT; ++r) acc[r] = bias;

    for (int i = 0; i < Ee / 4; ++i) {
        float4 w = wr[i];
#pragma unroll
        for (int r = 0; r < RT; ++r) {
            const float4 xv = *(const float4*)&as_[r * Ee + 4 * i];
            acc[r] += xv.x * w.x + xv.y * w.y + xv.z * w.z + xv.w * w.w;
        }
    }
#pragma unroll
    for (int r = 0; r < RT; ++r) out[(size_t)(r0 + r) * Ee + e] = acc[r];
}

// ---------------------------------------------------------------------------
extern "C" void kernel_launch(void* const* d_in, const int* in_sizes, int n_in,
                              void* d_out, int out_size, void* d_ws, size_t ws_size,
                              hipStream_t stream)
{
    const float* x  = (const float*)d_in[0];
    const float* Wk = (const float*)d_in[1];
    const float* Wq = (const float*)d_in[2];
    const float* Wv = (const float*)d_in[3];
    const float* Wp = (const float*)d_in[4];
    const float* bp = (const float*)d_in[5];
    float* out = (float*)d_out;

    float* ws   = (float*)d_ws;
    float* q    = ws;
    float* k    = ws + (size_t)QKVSZ;
    float* v    = ws + (size_t)2 * QKVSZ;
    float* attn = ws + (size_t)3 * QKVSZ;   // 32 MiB total fp32 scratch

    qkv_kernel<<<Bb * Ss / 32, 384, 0, stream>>>(x, Wk, Wq, Wv, q, k, v);
    attn_kernel<<<Bb * Hh * (Ss / 128), 256, 0, stream>>>(q, k, v, attn);
    proj_kernel<<<Bb * Ss / 16, 128, 0, stream>>>(attn, Wp, bp, out);
}

// Round 7
// 170.671 us; speedup vs baseline: 5.9405x; 1.2753x over previous
//
#include <hip/hip_runtime.h>
#include <hip/hip_bf16.h>

// Problem constants
constexpr int Bb  = 8;
constexpr int Ss  = 2048;
constexpr int Ee  = 128;
constexpr int Hh  = 8;
constexpr int HSs = 16;
constexpr int QKVSZ = Bb * Hh * Ss * HSs;  // 2,097,152 elements per tensor

typedef _Float16 f16;
typedef __attribute__((ext_vector_type(8)))  _Float16 f16x8;   // 8 f16 = 4 VGPRs
typedef __attribute__((ext_vector_type(16))) float f32x16;

// RTZ packed fp32x2 -> fp16x2 (one v_cvt_pkrtz_f16_f32); low half = first arg
__device__ __forceinline__ unsigned pack_rtz(float lo, float hi) {
    union { __fp16 __attribute__((ext_vector_type(2))) h; unsigned u; } c;
    c.h = __builtin_amdgcn_cvt_pkrtz(lo, hi);
    return c.u;
}
// RNE pair pack (two v_cvt_f16_f32, RNE rounding)
__device__ __forceinline__ unsigned pack_rne(float lo, float hi) {
    union { __attribute__((ext_vector_type(2))) _Float16 h; unsigned u; } c;
    c.h[0] = (f16)lo; c.h[1] = (f16)hi;
    return c.u;
}
// 8 consecutive floats -> f16x8 (RNE)
__device__ __forceinline__ f16x8 cvt8(const float* p) {
    float4 a = *(const float4*)p;
    float4 b = *(const float4*)(p + 4);
    f16x8 r;
    r[0] = (f16)a.x; r[1] = (f16)a.y; r[2] = (f16)a.z; r[3] = (f16)a.w;
    r[4] = (f16)b.x; r[5] = (f16)b.y; r[6] = (f16)b.z; r[7] = (f16)b.w;
    return r;
}

// ---------------------------------------------------------------------------
// Kernel A: Q/K/V projection as MFMA GEMM. C[16384,384] = X[16384,128] x W^T.
// Grid (128 M-tiles, 12 N-tiles); block = 4 waves; wave = 32 rows x 32 ch,
// K=128 in 8 steps of 32x32x16_f16. No LDS: A/B frags register-direct
// (X refetched 12x across N-tiles -> L2; W tiny -> L1).
// 32x32x16 layouts (verified in-round R6): A[m=lane&31][k=8h+j],
// B[k=8h+j][n=lane&31], C/D[row=(r&3)+8(r>>2)+4h][col=lane&31].
// ---------------------------------------------------------------------------
__global__ __launch_bounds__(256) void qkv_kernel(
    const float* __restrict__ x, const float* __restrict__ Wk,
    const float* __restrict__ Wq, const float* __restrict__ Wv,
    float* __restrict__ qo, float* __restrict__ ko, float* __restrict__ vo)
{
    const int wv = threadIdx.x >> 6, lane = threadIdx.x & 63;
    const int h = lane >> 5, n = lane & 31;
    const int mat = blockIdx.y >> 2;                 // 0=q, 1=k, 2=v
    const float* W = (mat == 0) ? Wq : ((mat == 1) ? Wk : Wv);
    const int c = ((blockIdx.y & 3) << 5) + n;       // channel 0..127 = head*16+d
    const int row = blockIdx.x * 128 + wv * 32 + n;  // A-row this lane stages
    const float* xr = x + (size_t)row * Ee + 8 * h;
    const float* wr = W + (size_t)c * Ee + 8 * h;

    f32x16 acc = {};
#pragma unroll
    for (int t = 0; t < 8; ++t) {
        f16x8 a = cvt8(xr + 16 * t);
        f16x8 b = cvt8(wr + 16 * t);
        acc = __builtin_amdgcn_mfma_f32_32x32x16_f16(a, b, acc, 0, 0, 0);
    }

    float* dst = (mat == 0) ? qo : ((mat == 1) ? ko : vo);
    const int head = c >> 4, d = c & 15;
    const int base = blockIdx.x * 128 + wv * 32 + 4 * h;
#pragma unroll
    for (int r = 0; r < 16; ++r) {
        int R = base + (r & 3) + 8 * (r >> 2);
        int b = R >> 11, s = R & 2047;
        dst[((size_t)(b * Hh + head) * Ss + s) * HSs + d] = acc[r];
    }
}

// ---------------------------------------------------------------------------
// Kernel B: MFMA flash attention, 64-key chunks (halved per-chunk overhead).
// Block = 4 waves, same (b,h); wave owns a 32-query tile.
//  S^T[key][q] = K(A) x Q^T(B)  -- 2x mfma_32x32x16_f16 per chunk
//  O^T[d][q]  += V^T(A, d rows 16..31 zero) x P^T -- 4x mfma per chunk
// Softmax state lane-local (q = lane&31 in both C layouts); one xor32/reduce.
// P^T C->B relayout in-register (shfl_xor 32 + selects).
// ---------------------------------------------------------------------------
constexpr float QSCALE = 5.770780163555854f;  // 4 * log2(e)

__device__ __forceinline__ void cb_exchange(const unsigned* pw, int h,
                                            f16x8& Blo, f16x8& Bhi) {
    unsigned exa = (unsigned)__shfl_xor((int)(h ? pw[0] : pw[2]), 32, 64);
    unsigned exb = (unsigned)__shfl_xor((int)(h ? pw[1] : pw[3]), 32, 64);
    unsigned exc = (unsigned)__shfl_xor((int)(h ? pw[4] : pw[6]), 32, 64);
    unsigned exd = (unsigned)__shfl_xor((int)(h ? pw[5] : pw[7]), 32, 64);
    union { unsigned u[4]; f16x8 v; } B1, B2;
    if (h == 0) {
        B1.u[0] = pw[0]; B1.u[1] = pw[1]; B1.u[2] = exa; B1.u[3] = exb;
        B2.u[0] = pw[4]; B2.u[1] = pw[5]; B2.u[2] = exc; B2.u[3] = exd;
    } else {
        B1.u[0] = exa; B1.u[1] = exb; B1.u[2] = pw[2]; B1.u[3] = pw[3];
        B2.u[0] = exc; B2.u[1] = exd; B2.u[2] = pw[6]; B2.u[3] = pw[7];
    }
    Blo = B1.v; Bhi = B2.v;
}

__global__ __launch_bounds__(256) void attn_kernel(
    const float* __restrict__ qg, const float* __restrict__ kg,
    const float* __restrict__ vg, float* __restrict__ og)
{
    __shared__ __align__(16) f16 Ks[64 * 24];   // [key][d 0..15], 48B rows, 3KB
    __shared__ __align__(16) f16 Vt[32 * 72];   // [d][key 0..63], 144B rows, 4.5KB

    const int bh   = blockIdx.x >> 4;           // 0..63
    const int qblk = blockIdx.x & 15;
    const int wv   = threadIdx.x >> 6;
    const int lane = threadIdx.x & 63;
    const int h    = lane >> 5;
    const int q31  = lane & 31;
    const int qbase = qblk * 128 + wv * 32;

    // zero Vt rows 16..31 once (PV M-padding); staging never touches them
    for (int i = threadIdx.x; i < 576; i += 256) ((unsigned*)Vt)[576 + i] = 0u;

    // Q B-frag: lane holds Q[q=q31][d=8h+j] * QSCALE, whole K loop
    f16x8 qf;
    {
        const float* qp = qg + ((size_t)bh * Ss + qbase + q31) * HSs + 8 * h;
#pragma unroll
        for (int j = 0; j < 8; ++j) qf[j] = (f16)(qp[j] * QSCALE);
    }

    // staging: thread owns float4 of K and V (key = tid>>2, d = (tid&3)*4)
    const float4* kp = (const float4*)(kg + (size_t)bh * Ss * HSs) + threadIdx.x;
    const float4* vp = (const float4*)(vg + (size_t)bh * Ss * HSs) + threadIdx.x;
    float4 kreg = *kp, vreg = *vp;
    const int skey = threadIdx.x >> 2;
    const int sd   = (threadIdx.x & 3) * 4;

    f32x16 acc = {};
    const f32x16 z16 = {};
    float m = -1e30f, l = 0.f;

    for (int it = 0; it < Ss / 64; ++it) {
        __syncthreads();   // previous chunk's readers done
        *(unsigned*)&Ks[skey * 24 + sd]     = pack_rne(kreg.x, kreg.y);
        *(unsigned*)&Ks[skey * 24 + sd + 2] = pack_rne(kreg.z, kreg.w);
        Vt[(sd + 0) * 72 + skey] = (f16)vreg.x;
        Vt[(sd + 1) * 72 + skey] = (f16)vreg.y;
        Vt[(sd + 2) * 72 + skey] = (f16)vreg.z;
        Vt[(sd + 3) * 72 + skey] = (f16)vreg.w;
        __syncthreads();
        if (it < Ss / 64 - 1) { kp += 256; vp += 256; kreg = *kp; vreg = *vp; }

        // S^T = K x Q^T for key groups 0..31 and 32..63
        f16x8 ka0 = *(const f16x8*)&Ks[q31 * 24 + 8 * h];
        f16x8 ka1 = *(const f16x8*)&Ks[(32 + q31) * 24 + 8 * h];
        f32x16 st0 = __builtin_amdgcn_mfma_f32_32x32x16_f16(ka0, qf, z16, 0, 0, 0);
        f32x16 st1 = __builtin_amdgcn_mfma_f32_32x32x16_f16(ka1, qf, z16, 0, 0, 0);
        // lane: S^T[key = 32*g + (r&3)+8*(r>>2)+4h][q=q31]

        // online softmax over 64 keys (32 in-lane + one xor32 per reduction)
        float mx = st0[0];
#pragma unroll
        for (int i = 1; i < 16; ++i) mx = fmaxf(mx, st0[i]);
#pragma unroll
        for (int i = 0; i < 16; ++i) mx = fmaxf(mx, st1[i]);
        mx = fmaxf(mx, __shfl_xor(mx, 32, 64));
        const float mnew = fmaxf(m, mx);
        const float corr = __builtin_amdgcn_exp2f(m - mnew);
        float p0[16], p1[16];
        float rs = 0.f;
#pragma unroll
        for (int i = 0; i < 16; ++i) { p0[i] = __builtin_amdgcn_exp2f(st0[i] - mnew); rs += p0[i]; }
#pragma unroll
        for (int i = 0; i < 16; ++i) { p1[i] = __builtin_amdgcn_exp2f(st1[i] - mnew); rs += p1[i]; }
        rs += __shfl_xor(rs, 32, 64);
        l = l * corr + rs;
#pragma unroll
        for (int r = 0; r < 8; ++r) acc[r] *= corr;   // only d<16 regs live
        m = mnew;

        // pack P^T pairs and relayout C->B for both key groups
        unsigned pw0[8], pw1[8];
#pragma unroll
        for (int r = 0; r < 8; ++r) pw0[r] = pack_rtz(p0[2 * r], p0[2 * r + 1]);
#pragma unroll
        for (int r = 0; r < 8; ++r) pw1[r] = pack_rtz(p1[2 * r], p1[2 * r + 1]);
        f16x8 B1, B2, B3, B4;
        cb_exchange(pw0, h, B1, B2);   // keys 0..15, 16..31
        cb_exchange(pw1, h, B3, B4);   // keys 32..47, 48..63

        // O^T += V^T x P^T over the 4 key groups of 16
        f16x8 va0 = *(const f16x8*)&Vt[q31 * 72 +  0 + 8 * h];
        f16x8 va1 = *(const f16x8*)&Vt[q31 * 72 + 16 + 8 * h];
        f16x8 va2 = *(const f16x8*)&Vt[q31 * 72 + 32 + 8 * h];
        f16x8 va3 = *(const f16x8*)&Vt[q31 * 72 + 48 + 8 * h];
        acc = __builtin_amdgcn_mfma_f32_32x32x16_f16(va0, B1, acc, 0, 0, 0);
        acc = __builtin_amdgcn_mfma_f32_32x32x16_f16(va1, B2, acc, 0, 0, 0);
        acc = __builtin_amdgcn_mfma_f32_32x32x16_f16(va2, B3, acc, 0, 0, 0);
        acc = __builtin_amdgcn_mfma_f32_32x32x16_f16(va3, B4, acc, 0, 0, 0);
    }

    // write: lane owns q=q31, d = 4h..4h+3 (regs 0-3), 8+4h.. (regs 4-7)
    const float inv = 1.f / l;
    const int b = bh >> 3, head = bh & 7;
    float* op = og + ((size_t)b * Ss + qbase + q31) * Ee + head * HSs + 4 * h;
    float4 r0 = { acc[0] * inv, acc[1] * inv, acc[2] * inv, acc[3] * inv };
    float4 r1 = { acc[4] * inv, acc[5] * inv, acc[6] * inv, acc[7] * inv };
    *(float4*)op = r0;
    *(float4*)(op + 8) = r1;
}

// ---------------------------------------------------------------------------
// Kernel C: output projection as MFMA GEMM + bias.
// C[16384,128] = attn[16384,128] x Wp^T + bp. Grid (128, 4); coalesced stores.
// ---------------------------------------------------------------------------
__global__ __launch_bounds__(256) void proj_kernel(
    const float* __restrict__ attn, const float* __restrict__ Wp,
    const float* __restrict__ bp, float* __restrict__ out)
{
    const int wv = threadIdx.x >> 6, lane = threadIdx.x & 63;
    const int h = lane >> 5, n = lane & 31;
    const int e = (blockIdx.y << 5) + n;             // output channel
    const int row = blockIdx.x * 128 + wv * 32 + n;  // A-row this lane stages
    const float* ar = attn + (size_t)row * Ee + 8 * h;
    const float* wr = Wp + (size_t)e * Ee + 8 * h;

    f32x16 acc = {};
#pragma unroll
    for (int t = 0; t < 8; ++t) {
        f16x8 a = cvt8(ar + 16 * t);
        f16x8 b = cvt8(wr + 16 * t);
        acc = __builtin_amdgcn_mfma_f32_32x32x16_f16(a, b, acc, 0, 0, 0);
    }

    const float bias = bp[e];
    const int base = blockIdx.x * 128 + wv * 32 + 4 * h;
#pragma unroll
    for (int r = 0; r < 16; ++r) {
        int R = base + (r & 3) + 8 * (r >> 2);
        out[(size_t)R * Ee + e] = acc[r] + bias;
    }
}

// ---------------------------------------------------------------------------
extern "C" void kernel_launch(void* const* d_in, const int* in_sizes, int n_in,
                              void* d_out, int out_size, void* d_ws, size_t ws_size,
                              hipStream_t stream)
{
    const float* x  = (const float*)d_in[0];
    const float* Wk = (const float*)d_in[1];
    const float* Wq = (const float*)d_in[2];
    const float* Wv = (const float*)d_in[3];
    const float* Wp = (const float*)d_in[4];
    const float* bp = (const float*)d_in[5];
    float* out = (float*)d_out;

    float* ws   = (float*)d_ws;
    float* q    = ws;
    float* k    = ws + (size_t)QKVSZ;
    float* v    = ws + (size_t)2 * QKVSZ;
    float* attn = ws + (size_t)3 * QKVSZ;   // 32 MiB total fp32 scratch

    qkv_kernel<<<dim3(Bb * Ss / 128, 12), 256, 0, stream>>>(x, Wk, Wq, Wv, q, k, v);
    attn_kernel<<<Bb * Hh * (Ss / 128), 256, 0, stream>>>(q, k, v, attn);
    proj_kernel<<<dim3(Bb * Ss / 128, 4), 256, 0, stream>>>(attn, Wp, bp, out);
}

// Round 8
// 158.099 us; speedup vs baseline: 6.4129x; 1.0795x over previous
//
#include <hip/hip_runtime.h>
#include <hip/hip_bf16.h>

// Problem constants
constexpr int Bb  = 8;
constexpr int Ss  = 2048;
constexpr int Ee  = 128;
constexpr int Hh  = 8;
constexpr int HSs = 16;
constexpr int QKVSZ = Bb * Hh * Ss * HSs;  // 2,097,152 elements per tensor

typedef _Float16 f16;
typedef __attribute__((ext_vector_type(8)))  _Float16 f16x8;   // 8 f16 = 4 VGPRs
typedef __attribute__((ext_vector_type(16))) float f32x16;

constexpr float QSCALE = 5.770780163555854f;  // 4 * log2(e); folded into stored k

// RTZ packed fp32x2 -> fp16x2 (one v_cvt_pkrtz_f16_f32); low half = first arg
__device__ __forceinline__ unsigned pack_rtz(float lo, float hi) {
    union { __fp16 __attribute__((ext_vector_type(2))) h; unsigned u; } c;
    c.h = __builtin_amdgcn_cvt_pkrtz(lo, hi);
    return c.u;
}
// RNE pair pack
__device__ __forceinline__ unsigned pack_rne(float lo, float hi) {
    union { __attribute__((ext_vector_type(2))) _Float16 h; unsigned u; } c;
    c.h[0] = (f16)lo; c.h[1] = (f16)hi;
    return c.u;
}

// ---------------------------------------------------------------------------
// Prep: fp32 -> fp16 one-time conversions into workspace.
// ---------------------------------------------------------------------------
__global__ __launch_bounds__(256) void prep_x(const float* __restrict__ x,
                                              f16* __restrict__ xh) {
    int i = (blockIdx.x * 256 + threadIdx.x) * 4;
    float4 v = *(const float4*)(x + i);
    union { f16 h[4]; uint2 u; } c;
    c.h[0] = (f16)v.x; c.h[1] = (f16)v.y; c.h[2] = (f16)v.z; c.h[3] = (f16)v.w;
    *(uint2*)(xh + i) = c.u;
}
__global__ __launch_bounds__(256) void prep_w(
    const float* __restrict__ Wq, const float* __restrict__ Wk,
    const float* __restrict__ Wv, const float* __restrict__ Wp,
    f16* __restrict__ wh)   // wh = [wq(16K) | wk(16K) | wv(16K) | wp(16K)]
{
    int i = (blockIdx.x * 256 + threadIdx.x) * 4;
    const float* src = (i < 16384) ? (Wq + i)
                     : (i < 32768) ? (Wk + i - 16384)
                     : (i < 49152) ? (Wv + i - 32768) : (Wp + i - 49152);
    float4 v = *(const float4*)src;
    union { f16 h[4]; uint2 u; } c;
    c.h[0] = (f16)v.x; c.h[1] = (f16)v.y; c.h[2] = (f16)v.z; c.h[3] = (f16)v.w;
    *(uint2*)(wh + i) = c.u;
}

// ---------------------------------------------------------------------------
// Kernel A: Q/K/V projection, all-f16 MFMA GEMM. Grid (128 M-tiles, 3 mats).
// Wave = 32 rows; A-frags (X rows) loaded once, reused over 4 channel groups.
// k output scaled by QSCALE (fp32, pre-round). v stored in MFMA-A-frag
// swizzled order so attention stages it with pure 16B copies:
//   v element (s,d) -> bh*32768 + (s>>6)*1024 + ((s>>4)&3)*256
//                      + ((s>>3)&1)*128 + d*8 + (s&7)     [halves]
// 32x32x16 layouts: A[m=lane&31][k=8h+j], B[k=8h+j][n=lane&31],
// C/D[row=(r&3)+8(r>>2)+4h][col=lane&31].
// ---------------------------------------------------------------------------
__global__ __launch_bounds__(256) void qkv_kernel(
    const f16* __restrict__ xh, const f16* __restrict__ wh,
    f16* __restrict__ qo, f16* __restrict__ ko, f16* __restrict__ vo)
{
    const int mat  = blockIdx.y;                 // 0=q,1=k,2=v
    const f16* W   = wh + mat * 16384;
    const int wv_  = threadIdx.x >> 6, lane = threadIdx.x & 63;
    const int h    = lane >> 5, n31 = lane & 31;
    const int rowbase = blockIdx.x * 128 + wv_ * 32;

    const f16* xr = xh + (size_t)(rowbase + n31) * Ee + 8 * h;
    f16x8 A[8];
#pragma unroll
    for (int t = 0; t < 8; ++t) A[t] = *(const f16x8*)(xr + 16 * t);

    f16* dst = (mat == 0) ? qo : ((mat == 1) ? ko : vo);
    const float scale = (mat == 1) ? QSCALE : 1.f;

#pragma unroll
    for (int g = 0; g < 4; ++g) {
        const int c = g * 32 + n31;              // channel = head*16+d
        const f16* wr = W + (size_t)c * Ee + 8 * h;
        f32x16 acc = {};
#pragma unroll
        for (int t = 0; t < 8; ++t)
            acc = __builtin_amdgcn_mfma_f32_32x32x16_f16(A[t], *(const f16x8*)(wr + 16 * t), acc, 0, 0, 0);

        const int head = c >> 4, d = c & 15;
#pragma unroll
        for (int r = 0; r < 16; ++r) {
            const int R = rowbase + (r & 3) + 8 * (r >> 2) + 4 * h;
            const int b = R >> 11, s = R & 2047;
            const int bh = b * Hh + head;
            f16 val = (f16)(acc[r] * scale);
            if (mat == 2) {
                dst[(size_t)bh * 32768 + (s >> 6) * 1024 + ((s >> 4) & 3) * 256
                    + ((s >> 3) & 1) * 128 + d * 8 + (s & 7)] = val;
            } else {
                dst[((size_t)bh * Ss + s) * HSs + d] = val;
            }
        }
    }
}

// ---------------------------------------------------------------------------
// Kernel B: MFMA flash attention, f16 I/O, 64-key chunks, copy-only staging.
// Block = 4 waves, same (b,h); wave owns 32 queries.
//  S^T[key][q] = K(A) x Q^T(B); O^T[d][q] += V^T(A, frag-staged) x P^T(B).
// Softmax state lane-local (q = lane&31); P^T C->B relayout via shfl_xor 32.
// XCD swizzle: 16 q-blocks of each bh land on one XCD (K/V L2-resident).
// ---------------------------------------------------------------------------
__device__ __forceinline__ void cb_exchange(const unsigned* pw, int h,
                                            f16x8& Blo, f16x8& Bhi) {
    unsigned exa = (unsigned)__shfl_xor((int)(h ? pw[0] : pw[2]), 32, 64);
    unsigned exb = (unsigned)__shfl_xor((int)(h ? pw[1] : pw[3]), 32, 64);
    unsigned exc = (unsigned)__shfl_xor((int)(h ? pw[4] : pw[6]), 32, 64);
    unsigned exd = (unsigned)__shfl_xor((int)(h ? pw[5] : pw[7]), 32, 64);
    union { unsigned u[4]; f16x8 v; } B1, B2;
    if (h == 0) {
        B1.u[0] = pw[0]; B1.u[1] = pw[1]; B1.u[2] = exa; B1.u[3] = exb;
        B2.u[0] = pw[4]; B2.u[1] = pw[5]; B2.u[2] = exc; B2.u[3] = exd;
    } else {
        B1.u[0] = exa; B1.u[1] = exb; B1.u[2] = pw[2]; B1.u[3] = pw[3];
        B2.u[0] = exc; B2.u[1] = exd; B2.u[2] = pw[6]; B2.u[3] = pw[7];
    }
    Blo = B1.v; Bhi = B2.v;
}

__global__ __launch_bounds__(256) void attn_kernel(
    const f16* __restrict__ qg, const f16* __restrict__ kg,
    const f16* __restrict__ vg, f16* __restrict__ og)
{
    __shared__ __align__(16) f16 Ks[64 * 24];    // [key][d], 48B rows, 3KB
    __shared__ __align__(16) f16 Vf[4 * 64 * 8]; // A-frag order [g][lane][j], 4KB

    // XCD-aware decode: bh = xcd*8 + (w>>4), qblk = w&15
    const int blk  = blockIdx.x;
    const int w_   = blk >> 3;
    const int bh   = (blk & 7) * 8 + (w_ >> 4);
    const int qblk = w_ & 15;
    const int wv_  = threadIdx.x >> 6;
    const int lane = threadIdx.x & 63;
    const int h    = lane >> 5;
    const int q31  = lane & 31;
    const int qbase = qblk * 128 + wv_ * 32;

    // zero Vf pad slots (lane&31 >= 16) once; staging never writes them
    {
        const int i = threadIdx.x & 127;   // 128 distinct 16B chunks
        if (threadIdx.x < 128)
            *(uint4*)&Vf[((i >> 5) * 512 + ((i >> 4) & 1) * 256 + 128 + (i & 15) * 8)] = (uint4){0,0,0,0};
    }

    // Q B-frag: direct b128 (QSCALE folded into k)
    const f16x8 qf = *(const f16x8*)(qg + ((size_t)bh * Ss + qbase + q31) * HSs + 8 * h);

    // staging: thread t<128 copies 16B of K, t>=128 copies 16B of V(frag order)
    const bool isK = threadIdx.x < 128;
    const int  i   = threadIdx.x & 127;
    const f16* gsrc = isK ? (kg + ((size_t)bh * Ss) * HSs + i * 8)
                          : (vg + (size_t)bh * 32768 + i * 8);
    f16* ldst = isK ? &Ks[(i >> 1) * 24 + (i & 1) * 8]
                    : &Vf[(i >> 5) * 512 + ((i >> 4) & 1) * 256 + (i & 15) * 8];
    f16x8 sreg = *(const f16x8*)gsrc;

    f32x16 acc = {};
    const f32x16 z16 = {};
    float m = -1e30f, l = 0.f;

    for (int it = 0; it < Ss / 64; ++it) {
        __syncthreads();                    // previous chunk's readers done
        *(f16x8*)ldst = sreg;
        __syncthreads();
        if (it < Ss / 64 - 1) { gsrc += 1024; sreg = *(const f16x8*)gsrc; }

        // S^T = K x Q^T for key groups 0..31, 32..63
        f16x8 ka0 = *(const f16x8*)&Ks[q31 * 24 + 8 * h];
        f16x8 ka1 = *(const f16x8*)&Ks[(32 + q31) * 24 + 8 * h];
        f32x16 st0 = __builtin_amdgcn_mfma_f32_32x32x16_f16(ka0, qf, z16, 0, 0, 0);
        f32x16 st1 = __builtin_amdgcn_mfma_f32_32x32x16_f16(ka1, qf, z16, 0, 0, 0);

        // online softmax over 64 keys (in-lane trees + one xor32 each)
        float mx = st0[0];
#pragma unroll
        for (int t = 1; t < 16; ++t) mx = fmaxf(mx, st0[t]);
#pragma unroll
        for (int t = 0; t < 16; ++t) mx = fmaxf(mx, st1[t]);
        mx = fmaxf(mx, __shfl_xor(mx, 32, 64));
        const float mnew = fmaxf(m, mx);
        const float corr = __builtin_amdgcn_exp2f(m - mnew);
        float p0[16], p1[16];
        float rs = 0.f;
#pragma unroll
        for (int t = 0; t < 16; ++t) { p0[t] = __builtin_amdgcn_exp2f(st0[t] - mnew); rs += p0[t]; }
#pragma unroll
        for (int t = 0; t < 16; ++t) { p1[t] = __builtin_amdgcn_exp2f(st1[t] - mnew); rs += p1[t]; }
        rs += __shfl_xor(rs, 32, 64);
        l = l * corr + rs;
#pragma unroll
        for (int r = 0; r < 8; ++r) acc[r] *= corr;   // only d<16 regs live
        m = mnew;

        // pack P^T pairs, relayout C->B
        unsigned pw0[8], pw1[8];
#pragma unroll
        for (int r = 0; r < 8; ++r) pw0[r] = pack_rtz(p0[2 * r], p0[2 * r + 1]);
#pragma unroll
        for (int r = 0; r < 8; ++r) pw1[r] = pack_rtz(p1[2 * r], p1[2 * r + 1]);
        f16x8 B1, B2, B3, B4;
        cb_exchange(pw0, h, B1, B2);
        cb_exchange(pw1, h, B3, B4);

        // O^T += V^T x P^T over 4 key groups (A-frags direct from Vf)
        f16x8 va0 = *(const f16x8*)&Vf[0 * 512 + lane * 8];
        f16x8 va1 = *(const f16x8*)&Vf[1 * 512 + lane * 8];
        f16x8 va2 = *(const f16x8*)&Vf[2 * 512 + lane * 8];
        f16x8 va3 = *(const f16x8*)&Vf[3 * 512 + lane * 8];
        acc = __builtin_amdgcn_mfma_f32_32x32x16_f16(va0, B1, acc, 0, 0, 0);
        acc = __builtin_amdgcn_mfma_f32_32x32x16_f16(va1, B2, acc, 0, 0, 0);
        acc = __builtin_amdgcn_mfma_f32_32x32x16_f16(va2, B3, acc, 0, 0, 0);
        acc = __builtin_amdgcn_mfma_f32_32x32x16_f16(va3, B4, acc, 0, 0, 0);
    }

    // write O as f16: lane q31 owns d = {4h..4h+3} (regs0-3), {8+4h..} (regs4-7)
    const float inv = 1.f / l;
    const int b = bh >> 3, head = bh & 7;
    f16* op = og + ((size_t)b * Ss + qbase + q31) * Ee + head * HSs;
    uint2 lo = { pack_rne(acc[0] * inv, acc[1] * inv), pack_rne(acc[2] * inv, acc[3] * inv) };
    uint2 hi = { pack_rne(acc[4] * inv, acc[5] * inv), pack_rne(acc[6] * inv, acc[7] * inv) };
    *(uint2*)(op + 4 * h)     = lo;
    *(uint2*)(op + 8 + 4 * h) = hi;
}

// ---------------------------------------------------------------------------
// Kernel C: output projection, f16 operands, fp32 out + bias.
// Grid (128 M-tiles, 2 channel halves); A-regs reused over 2 groups.
// ---------------------------------------------------------------------------
__global__ __launch_bounds__(256) void proj_kernel(
    const f16* __restrict__ oh, const f16* __restrict__ wph,
    const float* __restrict__ bp, float* __restrict__ out)
{
    const int wv_ = threadIdx.x >> 6, lane = threadIdx.x & 63;
    const int h = lane >> 5, n31 = lane & 31;
    const int rowbase = blockIdx.x * 128 + wv_ * 32;

    const f16* ar = oh + (size_t)(rowbase + n31) * Ee + 8 * h;
    f16x8 A[8];
#pragma unroll
    for (int t = 0; t < 8; ++t) A[t] = *(const f16x8*)(ar + 16 * t);

#pragma unroll
    for (int g = 0; g < 2; ++g) {
        const int e = blockIdx.y * 64 + g * 32 + n31;
        const f16* wr = wph + (size_t)e * Ee + 8 * h;
        f32x16 acc = {};
#pragma unroll
        for (int t = 0; t < 8; ++t)
            acc = __builtin_amdgcn_mfma_f32_32x32x16_f16(A[t], *(const f16x8*)(wr + 16 * t), acc, 0, 0, 0);
        const float bias = bp[e];
#pragma unroll
        for (int r = 0; r < 16; ++r) {
            const int R = rowbase + (r & 3) + 8 * (r >> 2) + 4 * h;
            out[(size_t)R * Ee + e] = acc[r] + bias;
        }
    }
}

// ---------------------------------------------------------------------------
extern "C" void kernel_launch(void* const* d_in, const int* in_sizes, int n_in,
                              void* d_out, int out_size, void* d_ws, size_t ws_size,
                              hipStream_t stream)
{
    const float* x  = (const float*)d_in[0];
    const float* Wk = (const float*)d_in[1];
    const float* Wq = (const float*)d_in[2];
    const float* Wv = (const float*)d_in[3];
    const float* Wp = (const float*)d_in[4];
    const float* bp = (const float*)d_in[5];
    float* out = (float*)d_out;

    f16* ws = (f16*)d_ws;                    // all halves
    f16* xh = ws;                            // 2M
    f16* qh = ws + (size_t)QKVSZ;            // 2M
    f16* kh = ws + (size_t)2 * QKVSZ;        // 2M
    f16* vh = ws + (size_t)3 * QKVSZ;        // 2M (frag-swizzled)
    f16* oh = ws + (size_t)4 * QKVSZ;        // 2M
    f16* wh = ws + (size_t)5 * QKVSZ;        // 64K: wq|wk|wv|wp

    prep_x<<<QKVSZ / 1024, 256, 0, stream>>>(x, xh);
    prep_w<<<64, 256, 0, stream>>>(Wq, Wk, Wv, Wp, wh);
    qkv_kernel<<<dim3(Bb * Ss / 128, 3), 256, 0, stream>>>(xh, wh, qh, kh, vh);
    attn_kernel<<<Bb * Hh * (Ss / 128), 256, 0, stream>>>(qh, kh, vh, oh);
    proj_kernel<<<dim3(Bb * Ss / 128, 2), 256, 0, stream>>>(oh, wh + 49152, bp, out);
}